// Round 12
// baseline (48.811 us; speedup 1.0000x reference)
//
#include <hip/hip_runtime.h>
#include <hip/hip_bf16.h>

#define N_TOT 8192
#define B_HALF 4096
#define D_DIM 256
#define NQUAD 496            // sum floor((64-ti)/4): 4-tile units
#define NSING 96             // sum (64-ti)%4: 1-tile tail units

typedef __attribute__((ext_vector_type(4))) float f32x4;

// S8SCALE = sqrt(256 * 2*log2(e)). zq = fp8(S8SCALE * z/|z|), so the MFMA acc
// = S8SCALE^2 * sim = 256 * sim * 2*log2(e)  ->  exp(sim/T) = exp2(acc/256).
#define S8SCALE 27.178307f
#define LN2 0.69314718056f

// global->LDS direct (16B/lane). Dest must be wave-uniform; HW adds lane*16.
typedef __attribute__((address_space(3))) void lds_void;
typedef __attribute__((address_space(1))) const void glb_void;
__device__ __forceinline__ void gld16(const void* g, void* l) {
  __builtin_amdgcn_global_load_lds((glb_void*)g, (lds_void*)l, 16, 0, 0);
}

// ---- normalize -> fp8 zq + self(fp8-exact) + pos partials + zeroing --------
__global__ __launch_bounds__(256) void k_norm(const float* __restrict__ p1,
                                              const float* __restrict__ p2,
                                              unsigned int* __restrict__ zq,
                                              float* __restrict__ self,
                                              float* __restrict__ partials,
                                              float* __restrict__ rowsum,
                                              float* __restrict__ out) {
  int tid = threadIdx.x;
  int lane = tid & 63;
  int w = tid >> 6;                 // wave 0..3
  int i = blockIdx.x * 4 + w;       // pair index 0..4095
  if (blockIdx.x < 32) rowsum[blockIdx.x * 256 + tid] = 0.0f;
  if (blockIdx.x == 0 && tid == 0) out[0] = 0.0f;
  float4 a = *reinterpret_cast<const float4*>(p1 + (size_t)i * D_DIM + lane * 4);
  float4 b = *reinterpret_cast<const float4*>(p2 + (size_t)i * D_DIM + lane * 4);
  float ssa = a.x * a.x + a.y * a.y + a.z * a.z + a.w * a.w;
  float ssb = b.x * b.x + b.y * b.y + b.z * b.z + b.w * b.w;
  float d = a.x * b.x + a.y * b.y + a.z * b.z + a.w * b.w;
#pragma unroll
  for (int m = 1; m < 64; m <<= 1) {
    ssa += __shfl_xor(ssa, m, 64);
    ssb += __shfl_xor(ssb, m, 64);
    d += __shfl_xor(d, m, 64);
  }
  float na = fmaxf(sqrtf(ssa), 1e-8f);
  float nb = fmaxf(sqrtf(ssb), 1e-8f);
  float ia = S8SCALE / na, ib = S8SCALE / nb;

  int wa = __builtin_amdgcn_cvt_pk_fp8_f32(a.x * ia, a.y * ia, 0, false);
  wa = __builtin_amdgcn_cvt_pk_fp8_f32(a.z * ia, a.w * ia, wa, true);
  int wb = __builtin_amdgcn_cvt_pk_fp8_f32(b.x * ib, b.y * ib, 0, false);
  wb = __builtin_amdgcn_cvt_pk_fp8_f32(b.z * ib, b.w * ib, wb, true);
  zq[(size_t)i * 64 + lane] = (unsigned int)wa;
  zq[(size_t)(i + B_HALF) * 64 + lane] = (unsigned int)wb;

  // self-sim exactly as the MFMA will see it: sum of dequantized fp8 squares
  float va0 = __builtin_amdgcn_cvt_f32_fp8(wa, 0);
  float va1 = __builtin_amdgcn_cvt_f32_fp8(wa, 1);
  float va2 = __builtin_amdgcn_cvt_f32_fp8(wa, 2);
  float va3 = __builtin_amdgcn_cvt_f32_fp8(wa, 3);
  float vb0 = __builtin_amdgcn_cvt_f32_fp8(wb, 0);
  float vb1 = __builtin_amdgcn_cvt_f32_fp8(wb, 1);
  float vb2 = __builtin_amdgcn_cvt_f32_fp8(wb, 2);
  float vb3 = __builtin_amdgcn_cvt_f32_fp8(wb, 3);
  float sqa = va0 * va0 + va1 * va1 + va2 * va2 + va3 * va3;
  float sqb = vb0 * vb0 + vb1 * vb1 + vb2 * vb2 + vb3 * vb3;
#pragma unroll
  for (int m = 1; m < 64; m <<= 1) {
    sqa += __shfl_xor(sqa, m, 64);
    sqb += __shfl_xor(sqb, m, 64);
  }
  __shared__ float red[4];
  if (lane == 0) {
    self[i] = sqa * (1.0f / 256.0f);             // exponent domain (acc/256)
    self[i + B_HALF] = sqb * (1.0f / 256.0f);
    red[w] = -4.0f * d / (na * nb) * (1.0f / (float)N_TOT);
  }
  __syncthreads();
  if (tid == 0) partials[blockIdx.x] = red[0] + red[1] + red[2] + red[3];
}

// ---- symmetric fused fp8 GEMM + exp row/col sums ---------------------------
// fp8 e4m3 path: af (64 VGPR) direct from global; B staged in wave-private
// 2x4KB LDS dbufs (32KB/block total, no A-bounce) via global_load_lds with
// pre-swizzled source; counted vmcnt(4); zero barriers anywhere.
// __launch_bounds__(256,3): VGPR cap 170 -> 3 blocks/CU (12 waves).
template <int NT>
__global__ __launch_bounds__(256, 3) void k_simq(const unsigned int* __restrict__ zq,
                                                 float* __restrict__ rowsum) {
  __shared__ __align__(16) char S[32768]; // 4 waves x 2 x 4KB B dbufs

  constexpr int NHT = 2 * NT; // 64-col steps
  constexpr int NPH = 4 * NT; // staging phases (K halves of 128)

  // decode bid -> (ti, tj0)
  const int bid = blockIdx.x;
  int ti = 0, cum = 0, tj0;
  if constexpr (NT == 4) {
    while (cum + ((64 - ti) >> 2) <= bid) { cum += (64 - ti) >> 2; ++ti; }
    tj0 = ti + 4 * (bid - cum);
  } else {
    while (cum + ((64 - ti) & 3) <= bid) { cum += (64 - ti) & 3; ++ti; }
    tj0 = 64 - ((64 - ti) & 3) + (bid - cum);
  }
  const bool diag = (tj0 == ti);
  const int rowbase = ti * 128;
  const int colchunk = tj0 * 128;

  const int tid = threadIdx.x;
  const int lane = tid & 63;
  const int wid = tid >> 6;
  const int wm = wid >> 1;  // row half
  const int wn = wid & 1;   // col half
  const int hi = lane >> 4; // 0..3
  const int lo = lane & 15;
  const char* zb = (const char*)zq; // fp8 matrix, 256 B/row

  // ---- A fragments direct from global (one-time, L2-resident) ----
  // af[m][g]: lane reads 8B = k elems g*32+hi*8 .. +7 of row wm*64+m*16+lo
  long af[4][8]; // 64 VGPRs
#pragma unroll
  for (int m = 0; m < 4; ++m) {
    const char* rp = zb + ((size_t)(rowbase + wm * 64 + m * 16 + lo) << 8) + hi * 8;
#pragma unroll
    for (int g = 0; g < 8; ++g)
      af[m][g] = *reinterpret_cast<const long long*>(rp + g * 32);
  }
  __builtin_amdgcn_sched_barrier(0); // af loads issued before staging

  char* Bw = S + wid * 8192; // wave-private 2 x 4KB dbuf

  // per-lane source offset: row sub = lane>>3, 16B slot = (lane&7)^(lane>>3)
  const int laneoff = ((lane & 7) ^ (lane >> 3)) * 16 + (lane >> 3) * 256;

  // stage phase p: 32 cols x 128K(half kh=p&1) = 4KB = 4 gld16
  auto stage = [&](int p) {
    char* dst = Bw + (p & 1) * 4096;
    const char* src = zb + ((size_t)(colchunk + (p >> 1) * 64 + wn * 32) << 8) +
                      (p & 1) * 128 + laneoff;
#pragma unroll
    for (int i = 0; i < 4; ++i) gld16(src + i * 2048, dst + i * 1024);
  };

  stage(0);
  stage(1);

  float pr[4][4] = {}; // [m][r] per-row exp partials (rows of ti)

#pragma unroll 1
  for (int t = 0; t < NHT; ++t) {
    f32x4 acc[4][2];
#pragma unroll
    for (int m = 0; m < 4; ++m)
#pragma unroll
      for (int n = 0; n < 2; ++n) acc[m][n] = (f32x4){0.f, 0.f, 0.f, 0.f};

#pragma unroll
    for (int kh = 0; kh < 2; ++kh) {
      const int p = t * 2 + kh;
      const char* Bc = Bw + (p & 1) * 4096;

      // own-wave counted wait: phase p's 4 loads (and af) done; p+1 flies on
      if (p == NPH - 1) {
        asm volatile("s_waitcnt vmcnt(0)" ::: "memory");
      } else {
        asm volatile("s_waitcnt vmcnt(4)" ::: "memory");
      }
      __builtin_amdgcn_sched_barrier(0);

      // bf frag (n,ks): col crow=n*16+lo, 8B at swizzled slot
      unsigned long long bf[2][4];
#pragma unroll
      for (int n = 0; n < 2; ++n) {
        const int crow = n * 16 + lo;
        const char* rb = Bc + crow * 128 + (hi & 1) * 8;
        const int s7 = crow & 7;
#pragma unroll
        for (int ks = 0; ks < 4; ++ks)
          bf[n][ks] = *reinterpret_cast<const unsigned long long*>(
              rb + (((ks * 2 + (hi >> 1)) ^ s7) << 4));
      }
      asm volatile("s_waitcnt lgkmcnt(0)" ::: "memory");
      __builtin_amdgcn_sched_barrier(0);
      if (p + 2 < NPH) stage(p + 2); // refill the buffer just read

      __builtin_amdgcn_s_setprio(1);
#pragma unroll
      for (int ks = 0; ks < 4; ++ks)
#pragma unroll
        for (int m = 0; m < 4; ++m) {
          acc[m][0] = __builtin_amdgcn_mfma_f32_16x16x32_fp8_fp8(
              af[m][kh * 4 + ks], (long)bf[0][ks], acc[m][0], 0, 0, 0);
          acc[m][1] = __builtin_amdgcn_mfma_f32_16x16x32_fp8_fp8(
              af[m][kh * 4 + ks], (long)bf[1][ks], acc[m][1], 0, 0, 0);
        }
      __builtin_amdgcn_s_setprio(0);
      __builtin_amdgcn_sched_barrier(0);
    }

    // retire 64-col step: exponent = acc/256; row partials + col partials
    float pc[2] = {0.f, 0.f};
#pragma unroll
    for (int m = 0; m < 4; ++m)
#pragma unroll
      for (int n = 0; n < 2; ++n) {
        float e0 = __builtin_amdgcn_exp2f(acc[m][n][0] * (1.0f / 256.0f));
        float e1 = __builtin_amdgcn_exp2f(acc[m][n][1] * (1.0f / 256.0f));
        float e2 = __builtin_amdgcn_exp2f(acc[m][n][2] * (1.0f / 256.0f));
        float e3 = __builtin_amdgcn_exp2f(acc[m][n][3] * (1.0f / 256.0f));
        pr[m][0] += e0; pr[m][1] += e1; pr[m][2] += e2; pr[m][3] += e3;
        pc[n] += (e0 + e1) + (e2 + e3);
      }

    // col sums -> rows of tj (skip the diagonal tile: first 2 steps when diag)
    if (!(diag && t < 2)) {
#pragma unroll
      for (int n = 0; n < 2; ++n) {
        float v = pc[n];
        v += __shfl_xor(v, 16, 64);
        v += __shfl_xor(v, 32, 64);
        if (hi == 0)
          atomicAdd(&rowsum[colchunk + t * 64 + wn * 32 + n * 16 + lo], v);
      }
    }
  }

  // row sums -> rows of ti (reduce over the 16 col-lanes)
#pragma unroll
  for (int m = 0; m < 4; ++m)
#pragma unroll
    for (int r = 0; r < 4; ++r) {
      float s = pr[m][r];
      s += __shfl_xor(s, 1, 64);
      s += __shfl_xor(s, 2, 64);
      s += __shfl_xor(s, 4, 64);
      s += __shfl_xor(s, 8, 64);
      if (lo == 0)
        atomicAdd(&rowsum[rowbase + wm * 64 + m * 16 + hi * 4 + r], s);
    }
}

// ---- final: 32 blocks, out += sum(log(rowsum-exp2(self)))/n + partials -----
__global__ __launch_bounds__(256) void k_lse(const float* __restrict__ rowsum,
                                             const float* __restrict__ self,
                                             const float* __restrict__ partials,
                                             float* __restrict__ out) {
  int tid = threadIdx.x;
  int i = blockIdx.x * 256 + tid;
  float rs = rowsum[i] - __builtin_amdgcn_exp2f(self[i]);
  float v = __builtin_amdgcn_logf(rs) * (LN2 / (float)N_TOT); // v_log_f32 = log2
  if (tid < 32) v += partials[blockIdx.x * 32 + tid];
#pragma unroll
  for (int m = 1; m < 64; m <<= 1) v += __shfl_xor(v, m, 64);
  __shared__ float red[4];
  if ((tid & 63) == 0) red[tid >> 6] = v;
  __syncthreads();
  if (tid == 0) atomicAdd(out, red[0] + red[1] + red[2] + red[3]);
}

extern "C" void kernel_launch(void* const* d_in, const int* in_sizes, int n_in,
                              void* d_out, int out_size, void* d_ws, size_t ws_size,
                              hipStream_t stream) {
  const float* p1 = (const float*)d_in[0];
  const float* p2 = (const float*)d_in[1];
  float* out = (float*)d_out;
  char* ws = (char*)d_ws;

  unsigned int* zq = (unsigned int*)ws;                          // 2 MB fp8
  float* self = (float*)(ws + (size_t)N_TOT * D_DIM);            // 32 KB
  float* rowsum = self + N_TOT;                                  // 32 KB
  float* partials = rowsum + N_TOT;                              // 4 KB

  k_norm<<<B_HALF / 4, 256, 0, stream>>>(p1, p2, zq, self, partials, rowsum, out);
  k_simq<4><<<NQUAD, 256, 0, stream>>>(zq, rowsum);
  k_simq<1><<<NSING, 256, 0, stream>>>(zq, rowsum);
  k_lse<<<N_TOT / 256, 256, 0, stream>>>(rowsum, self, partials, out);
}